// Round 18
// baseline (116.353 us; speedup 1.0000x reference)
//
#include <hip/hip_runtime.h>

typedef unsigned short u16;
typedef unsigned int u32;
typedef float f32x4 __attribute__((ext_vector_type(4)));
typedef float f32x16 __attribute__((ext_vector_type(16)));
typedef short s16x8 __attribute__((ext_vector_type(8)));

#define B_ 2
#define N_ 2048
#define C_ 1024
#define H_ 16
#define BN_ (B_*N_)   // 4096 rows

#define EXP2F(x) __builtin_amdgcn_exp2f(x)   // v_exp_f32 (base-2 native)

// ---------- helpers ----------
__device__ __forceinline__ u16 f2bf(float f) {
  union { float f; unsigned u; } c; c.f = f;
  unsigned u = c.u;
  u = (u + 0x7fffu + ((u >> 16) & 1u)) >> 16;   // RNE
  return (u16)u;
}
__device__ __forceinline__ float bf2f(u16 h) {
  union { unsigned u; float f; } c; c.u = ((unsigned)h) << 16;
  return c.f;
}
// pack two f32 -> u32 of 2 bf16 via HW cvt (lo16 = src0, hi16 = src1; RNE)
__device__ __forceinline__ u32 pack2(float lo, float hi) {
  u32 r;
  asm("v_cvt_pk_bf16_f32 %0, %1, %2" : "=v"(r) : "v"(lo), "v"(hi));
  return r;
}
// swap: new_a[hi lanes] = old_b[partner], new_b[lo lanes] = old_a[partner].
// a and b MUST be distinct values (aliased self-swap was the R4 bug).
__device__ __forceinline__ void plswap(u32& a, u32& b) {
  asm volatile("v_permlane32_swap_b32 %0, %1" : "+v"(a), "+v"(b));
}
__device__ __forceinline__ void gload16(const u16* g, u16* l) {
  __builtin_amdgcn_global_load_lds(
      (const __attribute__((address_space(1))) unsigned*)g,
      (__attribute__((address_space(3))) unsigned*)l, 16, 0, 0);
}

// ---------- fused prep: x cast + qkv_w transpose + proj_w transpose ----------
__global__ __launch_bounds__(256) void k_prep(const float* __restrict__ x,
                                              u16* __restrict__ xb,
                                              const float* __restrict__ qkv_w,
                                              u16* __restrict__ wqkvT,
                                              const float* __restrict__ proj_w,
                                              u16* __restrict__ wprojT) {
  __shared__ float t[32][33];
  int bid = blockIdx.x;
  int tid = threadIdx.x;
  if (bid < 4096) {
    int i = bid * 256 + tid;
    float4 v = ((const float4*)x)[i];
    ushort4 r;
    r.x = f2bf(v.x); r.y = f2bf(v.y); r.z = f2bf(v.z); r.w = f2bf(v.w);
    ((ushort4*)xb)[i] = r;
    return;
  }
  const float* W; u16* Wt; int R, Cc, bx, by;
  if (bid < 7168) {
    int b = bid - 4096;
    bx = b % 96; by = b / 96;
    W = qkv_w; Wt = wqkvT; R = C_; Cc = 3 * C_;
  } else {
    int b = bid - 7168;
    bx = b & 31; by = b >> 5;
    W = proj_w; Wt = wprojT; R = C_; Cc = C_;
  }
  int tx = tid & 31, ty = tid >> 5;
  int c0 = bx * 32, r0 = by * 32;
#pragma unroll
  for (int i = 0; i < 4; ++i)
    t[ty + i * 8][tx] = W[(long)(r0 + ty + i * 8) * Cc + c0 + tx];
  __syncthreads();
#pragma unroll
  for (int i = 0; i < 4; ++i)
    Wt[(long)(c0 + ty + i * 8) * R + r0 + tx] = f2bf(t[tx][ty + i * 8]);
}

// ---------- QKV GEMM BK=64 + fused LN + fused V-transpose ----------
// 2-buffer LDS (64KB), counted vmcnt(8); T2 XOR swizzle (row&7 on 8 slots).
__global__ __launch_bounds__(256) void k_gemm_qkv_ln(const u16* __restrict__ A,
                                                     const u16* __restrict__ Bt,
                                                     const float* __restrict__ qg,
                                                     const float* __restrict__ qbeta,
                                                     const float* __restrict__ kg,
                                                     const float* __restrict__ kbeta,
                                                     u16* __restrict__ Qh,
                                                     u16* __restrict__ Kh,
                                                     u16* __restrict__ Vt) {
  const int K = C_;
  __shared__ u16 smem[32768];            // 64KB: a_t[2] @0, b_t[2] @16384
  int tid = threadIdx.x;
  int w = tid >> 6, l = tid & 63;
  int l15 = l & 15, lhi = l >> 4;
  int wm = w >> 1, wn = w & 1;
  int rowA = l >> 3;
  int colA = ((l & 7) ^ (rowA & 7)) * 8;     // pre-swizzled source slot
  int x0 = (lhi ^ (l15 & 7)) * 8;            // phys frag offsets (loop-invariant)
  int x1 = ((4 + lhi) ^ (l15 & 7)) * 8;
  const u16* Ab = A + (long)blockIdx.y * 128 * K;
  const u16* Bb = Bt + (long)blockIdx.x * 128 * K;
  f32x4 acc[4][4];
#pragma unroll
  for (int m = 0; m < 4; ++m)
#pragma unroll
    for (int n = 0; n < 4; ++n)
      acc[m][n] = (f32x4){0.f, 0.f, 0.f, 0.f};

  auto STAGE = [&](int k0, int bi) {
    u16* at = smem + bi * 8192;
    u16* bt = smem + 16384 + bi * 8192;
#pragma unroll
    for (int i = 0; i < 4; ++i) {
      int ci = i * 4 + w;
      gload16(Ab + (long)(ci * 8 + rowA) * K + k0 + colA, &at[ci * 512]);
      gload16(Bb + (long)(ci * 8 + rowA) * K + k0 + colA, &bt[ci * 512]);
    }
  };

  const int NS = K / 64;  // 16
  STAGE(0, 0);
  for (int t = 0; t < NS; ++t) {
    __builtin_amdgcn_s_barrier();          // compute on buf (t-1)&1 done
    if (t + 1 < NS) {
      STAGE((t + 1) * 64, (t + 1) & 1);
      asm volatile("s_waitcnt vmcnt(8)" ::: "memory");
    } else {
      asm volatile("s_waitcnt vmcnt(0)" ::: "memory");
    }
    __builtin_amdgcn_s_barrier();          // tile t staged for all waves
    const u16* at = smem + (t & 1) * 8192;
    const u16* bt = smem + 16384 + (t & 1) * 8192;
#pragma unroll
    for (int kk = 0; kk < 2; ++kk) {
      int xo = kk ? x1 : x0;
      s16x8 af[4], bfr[4];
#pragma unroll
      for (int m = 0; m < 4; ++m)
        af[m] = *(const s16x8*)&at[(wm * 64 + m * 16 + l15) * 64 + xo];
#pragma unroll
      for (int n = 0; n < 4; ++n)
        bfr[n] = *(const s16x8*)&bt[(wn * 64 + n * 16 + l15) * 64 + xo];
#pragma unroll
      for (int m = 0; m < 4; ++m)
#pragma unroll
        for (int n = 0; n < 4; ++n)
          acc[m][n] = __builtin_amdgcn_mfma_f32_16x16x32_bf16(af[m], bfr[n], acc[m][n], 0, 0, 0);
    }
  }

  // ---- fused epilogue ----
  int cb = blockIdx.x * 128 + wn * 64;   // warp col base (64 cols = 1 head)
  int s = cb >> 10;                      // 0=q 1=k 2=v
  int h = (cb & 1023) >> 6;
  int rowbase = blockIdx.y * 128 + wm * 64;

  if (s == 2) {
    // ---- V: in-LDS warp-local 64x64 transpose, write Vt directly ----
    __syncthreads();                     // staging LDS now reusable
    u16* tbuf = smem + w * 4608;         // 64 rows(d) x pitch 72 (9216 B/warp)
    u32* tb32 = (u32*)tbuf;
#pragma unroll
    for (int m = 0; m < 4; ++m)
#pragma unroll
      for (int n = 0; n < 4; ++n) {
        int d = n * 16 + l15;
#pragma unroll
        for (int r = 0; r < 4; r += 2)
          tb32[d * 36 + m * 8 + lhi * 2 + (r >> 1)] =
              pack2(acc[m][n][r], acc[m][n][r + 1]);
      }
    int b = rowbase >> 11;
    int nnb = rowbase & (N_ - 1);
    int bhv = b * H_ + h;
    int ch = (l & 7) * 8;
#pragma unroll
    for (int i = 0; i < 8; ++i) {
      int dl = i * 8 + (l >> 3);
      s16x8 vv = *(const s16x8*)&tbuf[dl * 72 + ch];
      *(s16x8*)&Vt[(long)(bhv * 64 + dl) * N_ + nnb + ch] = vv;
    }
  } else {
    const float* g = (s == 0) ? qg : kg;
    const float* be = (s == 0) ? qbeta : kbeta;
    u16* Oh = (s == 0) ? Qh : Kh;
    float sc = (s == 0) ? 0.125f * 1.44269504089f : 1.f;   // fold log2(e) for exp2 softmax
    float gv[4], bv[4];
#pragma unroll
    for (int n = 0; n < 4; ++n) { gv[n] = g[n * 16 + l15]; bv[n] = be[n * 16 + l15]; }
#pragma unroll
    for (int m = 0; m < 4; ++m) {
#pragma unroll
      for (int r = 0; r < 4; ++r) {
        float t = (acc[m][0][r] + acc[m][1][r]) + (acc[m][2][r] + acc[m][3][r]);
        t += __shfl_xor(t, 1); t += __shfl_xor(t, 2);
        t += __shfl_xor(t, 4); t += __shfl_xor(t, 8);
        float mean = t * (1.f / 64.f);
        float v0 = acc[m][0][r] - mean, v1 = acc[m][1][r] - mean;
        float v2 = acc[m][2][r] - mean, v3 = acc[m][3][r] - mean;
        float q2 = (v0 * v0 + v1 * v1) + (v2 * v2 + v3 * v3);
        q2 += __shfl_xor(q2, 1); q2 += __shfl_xor(q2, 2);
        q2 += __shfl_xor(q2, 4); q2 += __shfl_xor(q2, 8);
        float rs = rsqrtf(q2 * (1.f / 64.f) + 1e-6f);
        int row = rowbase + m * 16 + lhi * 4 + r;
        int b = row >> 11, nn = row & (N_ - 1);
        long ob = ((long)(b * H_ + h) * N_ + nn) * 64;
        float vv[4] = {v0, v1, v2, v3};
#pragma unroll
        for (int n = 0; n < 4; ++n)
          Oh[ob + n * 16 + l15] = f2bf(sc * (gv[n] * vv[n] * rs + bv[n]));
      }
    }
  }
}

// ---------- proj GEMM: 128x64 tiles (512 blocks -> 2/CU, 8 waves/CU) ----------
__global__ __launch_bounds__(256) void k_gemm_proj(const u16* __restrict__ A,
                                                   const u16* __restrict__ Bt,
                                                   float* __restrict__ Cout,
                                                   const float* __restrict__ bias,
                                                   int M, int N, int K) {
  __shared__ u16 a_t[2][128 * 64];   // 32KB
  __shared__ u16 b_t[2][64 * 64];    // 16KB
  int tid = threadIdx.x;
  int w = tid >> 6, l = tid & 63;
  int l15 = l & 15, lhi = l >> 4;
  int rowA = l >> 3;
  int colA = ((l & 7) ^ (rowA & 7)) * 8;
  int x0 = (lhi ^ (l15 & 7)) * 8;
  int x1 = ((4 + lhi) ^ (l15 & 7)) * 8;
  const u16* Ab = A + (long)blockIdx.y * 128 * K;
  const u16* Bb = Bt + (long)blockIdx.x * 64 * K;
  f32x4 acc[2][4];
#pragma unroll
  for (int m = 0; m < 2; ++m)
#pragma unroll
    for (int n = 0; n < 4; ++n)
      acc[m][n] = (f32x4){0.f, 0.f, 0.f, 0.f};

  auto STAGE = [&](int k0, int bi) {
#pragma unroll
    for (int i = 0; i < 4; ++i) {
      int ci = i * 4 + w;
      gload16(Ab + (long)(ci * 8 + rowA) * K + k0 + colA, &a_t[bi][ci * 512]);
    }
#pragma unroll
    for (int i = 0; i < 2; ++i) {
      int ci = i * 4 + w;
      gload16(Bb + (long)(ci * 8 + rowA) * K + k0 + colA, &b_t[bi][ci * 512]);
    }
  };

  const int NS = 1024 / 64;  // 16
  STAGE(0, 0);
  for (int t = 0; t < NS; ++t) {
    __builtin_amdgcn_s_barrier();
    if (t + 1 < NS) {
      STAGE((t + 1) * 64, (t + 1) & 1);
      asm volatile("s_waitcnt vmcnt(6)" ::: "memory");
    } else {
      asm volatile("s_waitcnt vmcnt(0)" ::: "memory");
    }
    __builtin_amdgcn_s_barrier();
    const u16* at = a_t[t & 1];
    const u16* bt = b_t[t & 1];
#pragma unroll
    for (int kk = 0; kk < 2; ++kk) {
      int xo = kk ? x1 : x0;
      s16x8 af[2], bfr[4];
#pragma unroll
      for (int m = 0; m < 2; ++m)
        af[m] = *(const s16x8*)&a_t[t & 1][(w * 32 + m * 16 + l15) * 64 + xo];
#pragma unroll
      for (int n = 0; n < 4; ++n)
        bfr[n] = *(const s16x8*)&bt[(n * 16 + l15) * 64 + xo];
#pragma unroll
      for (int m = 0; m < 2; ++m)
#pragma unroll
        for (int n = 0; n < 4; ++n)
          acc[m][n] = __builtin_amdgcn_mfma_f32_16x16x32_bf16(af[m], bfr[n], acc[m][n], 0, 0, 0);
      (void)at;
    }
  }
#pragma unroll
  for (int m = 0; m < 2; ++m) {
#pragma unroll
    for (int n = 0; n < 4; ++n) {
      int col = blockIdx.x * 64 + n * 16 + l15;
#pragma unroll
      for (int r = 0; r < 4; ++r) {
        int row = blockIdx.y * 128 + w * 32 + m * 16 + lhi * 4 + r;
        Cout[(long)row * N + col] = acc[m][n][r] + bias[col];
      }
    }
  }
}

// ---------- flash attention: 4-wave blocks, full KV range, NO-MAX softmax ----------
// Qh pre-scaled by (1/8)*log2(e); exp2-domain softmax without max tracking.
// Each block: 128 q-rows (wave w owns q w*32..w*32+31), all 2048 keys
// (NT=32 tiles of 64). No KV-split/merge — plain-sum softmax made the split
// unnecessary; occupancy comes from small blocks instead (32KB LDS ->
// 4-5 blocks/CU = 16-20 waves/CU, 4-wave barrier convoys, independent
// pipelines fill each other's stalls). permlane32_swap P-pack; lane-local
// lsum, one cross-half shuffle at end. Grid 1D 512, XCD swizzle.
__global__ __launch_bounds__(256, 4) void k_attn(const u16* __restrict__ Qh,
                                                 const u16* __restrict__ Kh,
                                                 const u16* __restrict__ Vt,
                                                 u16* __restrict__ O) {
  __shared__ u16 k_t[2][64 * 64];   // 16KB
  __shared__ u16 v_t[2][64 * 64];   // 16KB
  int tid = threadIdx.x;
  int w = tid >> 6, l = tid & 63;
  int l31 = l & 31, hi = l >> 5;
  int id = blockIdx.x;
  int swz = (id & 7) * 64 + (id >> 3);
  int bh = swz >> 4, qb = swz & 15;
  int b = bh >> 4, h = bh & 15;
  const u16* Qb = Qh + ((long)bh * N_ + qb * 128 + w * 32) * 64;
  const u16* Kb = Kh + (long)bh * N_ * 64;
  const u16* Vb = Vt + (long)bh * 64 * N_;

  s16x8 qf[4];
#pragma unroll
  for (int j = 0; j < 4; ++j)
    qf[j] = *(const s16x8*)&Qb[l31 * 64 + j * 16 + hi * 8];

  f32x16 acc0, acc1;
#pragma unroll
  for (int i = 0; i < 16; ++i) { acc0[i] = 0.f; acc1[i] = 0.f; }
  float lsum = 0.f;   // lane-local partial; cross-half once at end

  int off[2][4];
#pragma unroll
  for (int t = 0; t < 2; ++t)
#pragma unroll
    for (int j = 0; j < 4; ++j)
      off[t][j] = (t * 32 + l31) * 64 + (((j * 2 + hi) ^ (l & 7)) * 8);

  int srow = l >> 3;
  int scol = ((l & 7) ^ srow) * 8;

  auto STAGE = [&](int kt, int bi) {
#pragma unroll
    for (int i = 0; i < 2; ++i) {
      int ci = i * 4 + w;
      gload16(Kb + (long)(kt + ci * 8 + srow) * 64 + scol, &k_t[bi][ci * 512]);
      gload16(Vb + (long)(ci * 8 + srow) * N_ + kt + scol, &v_t[bi][ci * 512]);
    }
  };

  const int NT = N_ / 64;  // 32
  STAGE(0, 0);

  for (int t = 0; t < NT; ++t) {
    __builtin_amdgcn_s_barrier();
    if (t + 1 < NT) {
      STAGE((t + 1) * 64, (t + 1) & 1);
      asm volatile("s_waitcnt vmcnt(4)" ::: "memory");
    } else {
      asm volatile("s_waitcnt vmcnt(0)" ::: "memory");
    }
    __builtin_amdgcn_s_barrier();
    const u16* kb = k_t[t & 1];
    const u16* vb = v_t[t & 1];

    // ---- S^T = mfma(K, Q) ----
    f32x16 s0, s1;
#pragma unroll
    for (int i = 0; i < 16; ++i) { s0[i] = 0.f; s1[i] = 0.f; }
    __builtin_amdgcn_s_setprio(1);
#pragma unroll
    for (int j = 0; j < 4; ++j) {
      s16x8 kf0 = *(const s16x8*)&kb[off[0][j]];
      s0 = __builtin_amdgcn_mfma_f32_32x32x16_bf16(kf0, qf[j], s0, 0, 0, 0);
      s16x8 kf1 = *(const s16x8*)&kb[off[1][j]];
      s1 = __builtin_amdgcn_mfma_f32_32x32x16_bf16(kf1, qf[j], s1, 0, 0, 0);
    }
    __builtin_amdgcn_s_setprio(0);

    // ---- P = exp2(S), lane-local row-sum ----
#pragma unroll
    for (int i = 0; i < 16; ++i) {
      s0[i] = EXP2F(s0[i]);
      s1[i] = EXP2F(s1[i]);
    }
    f32x16 sm;
#pragma unroll
    for (int i = 0; i < 16; ++i) sm[i] = s0[i] + s1[i];
#pragma unroll
    for (int i = 0; i < 8; ++i) sm[i] += sm[i + 8];
#pragma unroll
    for (int i = 0; i < 4; ++i) sm[i] += sm[i + 4];
    lsum += (sm[0] + sm[1]) + (sm[2] + sm[3]);

    // ---- pack P into PV A-fragments (permlane32_swap) ----
    s16x8 pa[4];
#pragma unroll
    for (int g = 0; g < 4; ++g) {
      const f32x16& sv = (g < 2) ? s0 : s1;
      int o = (g & 1) * 8;
      u32 a = pack2(sv[o + 0], sv[o + 1]);
      u32 bb = pack2(sv[o + 4], sv[o + 5]);
      u32 c = pack2(sv[o + 2], sv[o + 3]);
      u32 d = pack2(sv[o + 6], sv[o + 7]);
      plswap(a, bb);
      plswap(c, d);
      union { u32 u[4]; s16x8 v; } fr;
      fr.u[0] = a; fr.u[1] = c; fr.u[2] = bb; fr.u[3] = d;
      pa[g] = fr.v;
    }

    // ---- O += P V ----
    __builtin_amdgcn_s_setprio(1);
#pragma unroll
    for (int j = 0; j < 4; ++j) {
      s16x8 vf0 = *(const s16x8*)&vb[off[0][j]];
      acc0 = __builtin_amdgcn_mfma_f32_32x32x16_bf16(pa[j], vf0, acc0, 0, 0, 0);
      s16x8 vf1 = *(const s16x8*)&vb[off[1][j]];
      acc1 = __builtin_amdgcn_mfma_f32_32x32x16_bf16(pa[j], vf1, acc1, 0, 0, 0);
    }
    __builtin_amdgcn_s_setprio(0);
  }

  // ---- epilogue: single cross-half lsum reduce + direct O write ----
  lsum += __shfl_xor(lsum, 32);
  int lsi = __float_as_int(lsum);
#pragma unroll
  for (int r = 0; r < 16; ++r) {
    int ql = (r & 3) + 8 * (r >> 2) + 4 * hi;
    float ls = __int_as_float(__builtin_amdgcn_ds_bpermute(ql << 2, lsi));
    float inv = 1.f / ls;
    int q = qb * 128 + w * 32 + ql;
    long ob = ((long)(b * N_ + q) * H_ + h) * 64 + l31;
    O[ob] = f2bf(acc0[r] * inv);
    O[ob + 32] = f2bf(acc1[r] * inv);
  }
}

// ---------- launch ----------
extern "C" void kernel_launch(void* const* d_in, const int* in_sizes, int n_in,
                              void* d_out, int out_size, void* d_ws, size_t ws_size,
                              hipStream_t stream) {
  const float* x      = (const float*)d_in[0];
  const float* qkv_w  = (const float*)d_in[1];
  const float* q_g    = (const float*)d_in[2];
  const float* q_b    = (const float*)d_in[3];
  const float* k_g    = (const float*)d_in[4];
  const float* k_b    = (const float*)d_in[5];
  const float* proj_w = (const float*)d_in[6];
  const float* proj_b = (const float*)d_in[7];
  float* out = (float*)d_out;

  char* ws = (char*)d_ws;
  // byte offsets (all 256-aligned)
  u16* xb     = (u16*)(ws + 0);                       //  8 MB  [4096][1024]
  u16* wqkvT  = (u16*)(ws + 8388608);                 //  6 MB  [3072][1024]
  u16* wprojT = (u16*)(ws + 14680064);                //  2 MB  [1024][1024]
  u16* Qh     = (u16*)(ws + 16777216);                //  8 MB  [32][2048][64]
  u16* Kh     = (u16*)(ws + 25165824);                //  8 MB
  u16* Vt     = (u16*)(ws + 41943040);                //  8 MB  [32][64][2048]
  u16* attnO  = xb;                                   // reuse (xb dead after QKV GEMM)

  k_prep<<<8192, 256, 0, stream>>>(x, xb, qkv_w, wqkvT, proj_w, wprojT);
  k_gemm_qkv_ln<<<dim3(24, 32), 256, 0, stream>>>(xb, wqkvT, q_g, q_b, k_g, k_b, Qh, Kh, Vt);
  k_attn<<<512, 256, 0, stream>>>(Qh, Kh, Vt, attnO);
  k_gemm_proj<<<dim3(16, 32), 256, 0, stream>>>(attnO, wprojT, out, proj_b, BN_, C_, C_);
}

// Round 21
// 114.903 us; speedup vs baseline: 1.0126x; 1.0126x over previous
//
#include <hip/hip_runtime.h>

typedef unsigned short u16;
typedef unsigned int u32;
typedef float f32x4 __attribute__((ext_vector_type(4)));
typedef float f32x16 __attribute__((ext_vector_type(16)));
typedef short s16x8 __attribute__((ext_vector_type(8)));

#define B_ 2
#define N_ 2048
#define C_ 1024
#define H_ 16
#define BN_ (B_*N_)   // 4096 rows

#define EXP2F(x) __builtin_amdgcn_exp2f(x)   // v_exp_f32 (base-2 native)

// ---------- helpers ----------
__device__ __forceinline__ u16 f2bf(float f) {
  union { float f; unsigned u; } c; c.f = f;
  unsigned u = c.u;
  u = (u + 0x7fffu + ((u >> 16) & 1u)) >> 16;   // RNE
  return (u16)u;
}
__device__ __forceinline__ float bf2f(u16 h) {
  union { unsigned u; float f; } c; c.u = ((unsigned)h) << 16;
  return c.f;
}
// pack two f32 -> u32 of 2 bf16 via HW cvt (lo16 = src0, hi16 = src1; RNE)
__device__ __forceinline__ u32 pack2(float lo, float hi) {
  u32 r;
  asm("v_cvt_pk_bf16_f32 %0, %1, %2" : "=v"(r) : "v"(lo), "v"(hi));
  return r;
}
// swap: new_a[hi lanes] = old_b[partner], new_b[lo lanes] = old_a[partner].
// a and b MUST be distinct values (aliased self-swap was the R4 bug).
__device__ __forceinline__ void plswap(u32& a, u32& b) {
  asm volatile("v_permlane32_swap_b32 %0, %1" : "+v"(a), "+v"(b));
}
__device__ __forceinline__ void gload16(const u16* g, u16* l) {
  __builtin_amdgcn_global_load_lds(
      (const __attribute__((address_space(1))) unsigned*)g,
      (__attribute__((address_space(3))) unsigned*)l, 16, 0, 0);
}

// ---------- fused prep: x cast + qkv_w transpose + proj_w transpose ----------
__global__ __launch_bounds__(256) void k_prep(const float* __restrict__ x,
                                              u16* __restrict__ xb,
                                              const float* __restrict__ qkv_w,
                                              u16* __restrict__ wqkvT,
                                              const float* __restrict__ proj_w,
                                              u16* __restrict__ wprojT) {
  __shared__ float t[32][33];
  int bid = blockIdx.x;
  int tid = threadIdx.x;
  if (bid < 4096) {
    int i = bid * 256 + tid;
    float4 v = ((const float4*)x)[i];
    ushort4 r;
    r.x = f2bf(v.x); r.y = f2bf(v.y); r.z = f2bf(v.z); r.w = f2bf(v.w);
    ((ushort4*)xb)[i] = r;
    return;
  }
  const float* W; u16* Wt; int R, Cc, bx, by;
  if (bid < 7168) {
    int b = bid - 4096;
    bx = b % 96; by = b / 96;
    W = qkv_w; Wt = wqkvT; R = C_; Cc = 3 * C_;
  } else {
    int b = bid - 7168;
    bx = b & 31; by = b >> 5;
    W = proj_w; Wt = wprojT; R = C_; Cc = C_;
  }
  int tx = tid & 31, ty = tid >> 5;
  int c0 = bx * 32, r0 = by * 32;
#pragma unroll
  for (int i = 0; i < 4; ++i)
    t[ty + i * 8][tx] = W[(long)(r0 + ty + i * 8) * Cc + c0 + tx];
  __syncthreads();
#pragma unroll
  for (int i = 0; i < 4; ++i)
    Wt[(long)(c0 + ty + i * 8) * R + r0 + tx] = f2bf(t[tx][ty + i * 8]);
}

// ---------- QKV GEMM BK=64 (R17-verified 128x128) + fused LN + V-transpose ----------
// 2-buffer LDS (64KB), counted vmcnt(8); T2 XOR swizzle. Grid 1D 768 with
// XCD swizzle (bijective, 768%8==0): each XCD owns 4 contiguous row-panels
// x all 6 col-panels -> A-panels L2-resident per XCD.
__global__ __launch_bounds__(256) void k_gemm_qkv_ln(const u16* __restrict__ A,
                                                     const u16* __restrict__ Bt,
                                                     const float* __restrict__ qg,
                                                     const float* __restrict__ qbeta,
                                                     const float* __restrict__ kg,
                                                     const float* __restrict__ kbeta,
                                                     u16* __restrict__ Qh,
                                                     u16* __restrict__ Kh,
                                                     u16* __restrict__ Vt) {
  const int K = C_;
  __shared__ u16 smem[32768];            // 64KB: a_t[2] @0, b_t[2] @16384
  int id = blockIdx.x;
  int swz = (id & 7) * 96 + (id >> 3);   // XCD-contiguous remap (bijective)
  int bx = swz % 24, by = swz / 24;
  int tid = threadIdx.x;
  int w = tid >> 6, l = tid & 63;
  int l15 = l & 15, lhi = l >> 4;
  int wm = w >> 1, wn = w & 1;
  int rowA = l >> 3;
  int colA = ((l & 7) ^ (rowA & 7)) * 8;     // pre-swizzled source slot
  int x0 = (lhi ^ (l15 & 7)) * 8;            // phys frag offsets (loop-invariant)
  int x1 = ((4 + lhi) ^ (l15 & 7)) * 8;
  const u16* Ab = A + (long)by * 128 * K;
  const u16* Bb = Bt + (long)bx * 128 * K;
  f32x4 acc[4][4];
#pragma unroll
  for (int m = 0; m < 4; ++m)
#pragma unroll
    for (int n = 0; n < 4; ++n)
      acc[m][n] = (f32x4){0.f, 0.f, 0.f, 0.f};

  auto STAGE = [&](int k0, int bi) {
    u16* at = smem + bi * 8192;
    u16* bt = smem + 16384 + bi * 8192;
#pragma unroll
    for (int i = 0; i < 4; ++i) {
      int ci = i * 4 + w;
      gload16(Ab + (long)(ci * 8 + rowA) * K + k0 + colA, &at[ci * 512]);
      gload16(Bb + (long)(ci * 8 + rowA) * K + k0 + colA, &bt[ci * 512]);
    }
  };

  const int NS = K / 64;  // 16
  STAGE(0, 0);
  for (int t = 0; t < NS; ++t) {
    __builtin_amdgcn_s_barrier();          // compute on buf (t-1)&1 done
    if (t + 1 < NS) {
      STAGE((t + 1) * 64, (t + 1) & 1);
      asm volatile("s_waitcnt vmcnt(8)" ::: "memory");
    } else {
      asm volatile("s_waitcnt vmcnt(0)" ::: "memory");
    }
    __builtin_amdgcn_s_barrier();          // tile t staged for all waves
    const u16* at = smem + (t & 1) * 8192;
    const u16* bt = smem + 16384 + (t & 1) * 8192;
#pragma unroll
    for (int kk = 0; kk < 2; ++kk) {
      int xo = kk ? x1 : x0;
      s16x8 af[4], bfr[4];
#pragma unroll
      for (int m = 0; m < 4; ++m)
        af[m] = *(const s16x8*)&at[(wm * 64 + m * 16 + l15) * 64 + xo];
#pragma unroll
      for (int n = 0; n < 4; ++n)
        bfr[n] = *(const s16x8*)&bt[(wn * 64 + n * 16 + l15) * 64 + xo];
#pragma unroll
      for (int m = 0; m < 4; ++m)
#pragma unroll
        for (int n = 0; n < 4; ++n)
          acc[m][n] = __builtin_amdgcn_mfma_f32_16x16x32_bf16(af[m], bfr[n], acc[m][n], 0, 0, 0);
    }
  }

  // ---- fused epilogue ----
  int cb = bx * 128 + wn * 64;           // warp col base (64 cols = 1 head)
  int s = cb >> 10;                      // 0=q 1=k 2=v
  int h = (cb & 1023) >> 6;
  int rowbase = by * 128 + wm * 64;

  if (s == 2) {
    // ---- V: in-LDS warp-local 64x64 transpose, write Vt directly ----
    __syncthreads();                     // staging LDS now reusable
    u16* tbuf = smem + w * 4608;         // 64 rows(d) x pitch 72 (9216 B/warp)
    u32* tb32 = (u32*)tbuf;
#pragma unroll
    for (int m = 0; m < 4; ++m)
#pragma unroll
      for (int n = 0; n < 4; ++n) {
        int d = n * 16 + l15;
#pragma unroll
        for (int r = 0; r < 4; r += 2)
          tb32[d * 36 + m * 8 + lhi * 2 + (r >> 1)] =
              pack2(acc[m][n][r], acc[m][n][r + 1]);
      }
    int b = rowbase >> 11;
    int nnb = rowbase & (N_ - 1);
    int bhv = b * H_ + h;
    int ch = (l & 7) * 8;
#pragma unroll
    for (int i = 0; i < 8; ++i) {
      int dl = i * 8 + (l >> 3);
      s16x8 vv = *(const s16x8*)&tbuf[dl * 72 + ch];
      *(s16x8*)&Vt[(long)(bhv * 64 + dl) * N_ + nnb + ch] = vv;
    }
  } else {
    const float* g = (s == 0) ? qg : kg;
    const float* be = (s == 0) ? qbeta : kbeta;
    u16* Oh = (s == 0) ? Qh : Kh;
    float sc = (s == 0) ? 0.125f * 1.44269504089f : 1.f;   // fold log2(e)
    float gv[4], bv[4];
#pragma unroll
    for (int n = 0; n < 4; ++n) { gv[n] = g[n * 16 + l15]; bv[n] = be[n * 16 + l15]; }
#pragma unroll
    for (int m = 0; m < 4; ++m) {
#pragma unroll
      for (int r = 0; r < 4; ++r) {
        float t = (acc[m][0][r] + acc[m][1][r]) + (acc[m][2][r] + acc[m][3][r]);
        t += __shfl_xor(t, 1); t += __shfl_xor(t, 2);
        t += __shfl_xor(t, 4); t += __shfl_xor(t, 8);
        float mean = t * (1.f / 64.f);
        float v0 = acc[m][0][r] - mean, v1 = acc[m][1][r] - mean;
        float v2 = acc[m][2][r] - mean, v3 = acc[m][3][r] - mean;
        float q2 = (v0 * v0 + v1 * v1) + (v2 * v2 + v3 * v3);
        q2 += __shfl_xor(q2, 1); q2 += __shfl_xor(q2, 2);
        q2 += __shfl_xor(q2, 4); q2 += __shfl_xor(q2, 8);
        float rs = rsqrtf(q2 * (1.f / 64.f) + 1e-6f);
        int row = rowbase + m * 16 + lhi * 4 + r;
        int b = row >> 11, nn = row & (N_ - 1);
        long ob = ((long)(b * H_ + h) * N_ + nn) * 64;
        float vv[4] = {v0, v1, v2, v3};
#pragma unroll
        for (int n = 0; n < 4; ++n)
          Oh[ob + n * 16 + l15] = f2bf(sc * (gv[n] * vv[n] * rs + bv[n]));
      }
    }
  }
}

// ---------- proj GEMM: 128x64 tiles (R17-verified) + XCD swizzle ----------
__global__ __launch_bounds__(256) void k_gemm_proj(const u16* __restrict__ A,
                                                   const u16* __restrict__ Bt,
                                                   float* __restrict__ Cout,
                                                   const float* __restrict__ bias,
                                                   int M, int N, int K) {
  __shared__ u16 a_t[2][128 * 64];   // 32KB
  __shared__ u16 b_t[2][64 * 64];    // 16KB
  int id = blockIdx.x;
  int swz = (id & 7) * 64 + (id >> 3);   // bijective (512%8==0)
  int bx = swz & 15, by = swz >> 4;
  int tid = threadIdx.x;
  int w = tid >> 6, l = tid & 63;
  int l15 = l & 15, lhi = l >> 4;
  int rowA = l >> 3;
  int colA = ((l & 7) ^ (rowA & 7)) * 8;
  int x0 = (lhi ^ (l15 & 7)) * 8;
  int x1 = ((4 + lhi) ^ (l15 & 7)) * 8;
  const u16* Ab = A + (long)by * 128 * K;
  const u16* Bb = Bt + (long)bx * 64 * K;
  f32x4 acc[2][4];
#pragma unroll
  for (int m = 0; m < 2; ++m)
#pragma unroll
    for (int n = 0; n < 4; ++n)
      acc[m][n] = (f32x4){0.f, 0.f, 0.f, 0.f};

  auto STAGE = [&](int k0, int bi) {
#pragma unroll
    for (int i = 0; i < 4; ++i) {
      int ci = i * 4 + w;
      gload16(Ab + (long)(ci * 8 + rowA) * K + k0 + colA, &a_t[bi][ci * 512]);
    }
#pragma unroll
    for (int i = 0; i < 2; ++i) {
      int ci = i * 4 + w;
      gload16(Bb + (long)(ci * 8 + rowA) * K + k0 + colA, &b_t[bi][ci * 512]);
    }
  };

  const int NS = 1024 / 64;  // 16
  STAGE(0, 0);
  for (int t = 0; t < NS; ++t) {
    __builtin_amdgcn_s_barrier();
    if (t + 1 < NS) {
      STAGE((t + 1) * 64, (t + 1) & 1);
      asm volatile("s_waitcnt vmcnt(6)" ::: "memory");
    } else {
      asm volatile("s_waitcnt vmcnt(0)" ::: "memory");
    }
    __builtin_amdgcn_s_barrier();
    const u16* at = a_t[t & 1];
    const u16* bt = b_t[t & 1];
#pragma unroll
    for (int kk = 0; kk < 2; ++kk) {
      int xo = kk ? x1 : x0;
      s16x8 af[2], bfr[4];
#pragma unroll
      for (int m = 0; m < 2; ++m)
        af[m] = *(const s16x8*)&at[(w * 32 + m * 16 + l15) * 64 + xo];
#pragma unroll
      for (int n = 0; n < 4; ++n)
        bfr[n] = *(const s16x8*)&bt[(n * 16 + l15) * 64 + xo];
#pragma unroll
      for (int m = 0; m < 2; ++m)
#pragma unroll
        for (int n = 0; n < 4; ++n)
          acc[m][n] = __builtin_amdgcn_mfma_f32_16x16x32_bf16(af[m], bfr[n], acc[m][n], 0, 0, 0);
    }
  }
#pragma unroll
  for (int m = 0; m < 2; ++m) {
#pragma unroll
    for (int n = 0; n < 4; ++n) {
      int col = bx * 64 + n * 16 + l15;
#pragma unroll
      for (int r = 0; r < 4; ++r) {
        int row = by * 128 + w * 32 + m * 16 + lhi * 4 + r;
        Cout[(long)row * N + col] = acc[m][n][r] + bias[col];
      }
    }
  }
}

// ---------- flash attention (R17-verified): 8-wave, in-block KV split ----------
// Qh pre-scaled by (1/8)*log2(e); exp2-domain NO-MAX softmax. Waves 0-3:
// keys 0..1023; waves 4-7: keys 1024..2047. permlane32_swap P-pack; deferred
// lsum cross-half. Grid 1D 512, XCD swizzle.
__global__ __launch_bounds__(512, 4) void k_attn(const u16* __restrict__ Qh,
                                                 const u16* __restrict__ Kh,
                                                 const u16* __restrict__ Vt,
                                                 u16* __restrict__ O) {
  __shared__ u16 k_t[2][2][64 * 64];   // [half][buf][.]  32KB
  __shared__ u16 v_t[2][2][64 * 64];   //                 32KB
  int tid = threadIdx.x;
  int w = tid >> 6, l = tid & 63;
  int half = w >> 2, wq = w & 3;
  int l31 = l & 31, hi = l >> 5;
  int id = blockIdx.x;
  int swz = (id & 7) * 64 + (id >> 3);
  int bh = swz >> 4, qb = swz & 15;
  int b = bh >> 4, h = bh & 15;
  const u16* Qb = Qh + ((long)bh * N_ + qb * 128 + wq * 32) * 64;
  const u16* Kb = Kh + ((long)bh * N_ + half * 1024) * 64;
  const u16* Vb = Vt + (long)bh * 64 * N_ + half * 1024;

  s16x8 qf[4];
#pragma unroll
  for (int j = 0; j < 4; ++j)
    qf[j] = *(const s16x8*)&Qb[l31 * 64 + j * 16 + hi * 8];

  f32x16 acc0, acc1;
#pragma unroll
  for (int i = 0; i < 16; ++i) { acc0[i] = 0.f; acc1[i] = 0.f; }
  float lsum = 0.f;   // lane-local partial; cross-half once at end

  int off[2][4];
#pragma unroll
  for (int t = 0; t < 2; ++t)
#pragma unroll
    for (int j = 0; j < 4; ++j)
      off[t][j] = (t * 32 + l31) * 64 + (((j * 2 + hi) ^ (l & 7)) * 8);

  int srow = l >> 3;
  int scol = ((l & 7) ^ srow) * 8;

  auto STAGE = [&](int kt, int bi) {
#pragma unroll
    for (int i = 0; i < 2; ++i) {
      int ci = i * 4 + wq;
      gload16(Kb + (long)(kt + ci * 8 + srow) * 64 + scol, &k_t[half][bi][ci * 512]);
      gload16(Vb + (long)(ci * 8 + srow) * N_ + kt + scol, &v_t[half][bi][ci * 512]);
    }
  };

  const int NT = 16;   // 1024 keys per half / 64
  STAGE(0, 0);

  for (int t = 0; t < NT; ++t) {
    __builtin_amdgcn_s_barrier();
    if (t + 1 < NT) {
      STAGE((t + 1) * 64, (t + 1) & 1);
      asm volatile("s_waitcnt vmcnt(4)" ::: "memory");
    } else {
      asm volatile("s_waitcnt vmcnt(0)" ::: "memory");
    }
    __builtin_amdgcn_s_barrier();
    const u16* kb = k_t[half][t & 1];
    const u16* vb = v_t[half][t & 1];

    // ---- S^T = mfma(K, Q) ----
    f32x16 s0, s1;
#pragma unroll
    for (int i = 0; i < 16; ++i) { s0[i] = 0.f; s1[i] = 0.f; }
    __builtin_amdgcn_s_setprio(1);
#pragma unroll
    for (int j = 0; j < 4; ++j) {
      s16x8 kf0 = *(const s16x8*)&kb[off[0][j]];
      s0 = __builtin_amdgcn_mfma_f32_32x32x16_bf16(kf0, qf[j], s0, 0, 0, 0);
      s16x8 kf1 = *(const s16x8*)&kb[off[1][j]];
      s1 = __builtin_amdgcn_mfma_f32_32x32x16_bf16(kf1, qf[j], s1, 0, 0, 0);
    }
    __builtin_amdgcn_s_setprio(0);

    // ---- P = exp2(S), lane-local row-sum ----
#pragma unroll
    for (int i = 0; i < 16; ++i) {
      s0[i] = EXP2F(s0[i]);
      s1[i] = EXP2F(s1[i]);
    }
    f32x16 sm;
#pragma unroll
    for (int i = 0; i < 16; ++i) sm[i] = s0[i] + s1[i];
#pragma unroll
    for (int i = 0; i < 8; ++i) sm[i] += sm[i + 8];
#pragma unroll
    for (int i = 0; i < 4; ++i) sm[i] += sm[i + 4];
    lsum += (sm[0] + sm[1]) + (sm[2] + sm[3]);

    // ---- pack P into PV A-fragments (permlane32_swap) ----
    s16x8 pa[4];
#pragma unroll
    for (int g = 0; g < 4; ++g) {
      const f32x16& sv = (g < 2) ? s0 : s1;
      int o = (g & 1) * 8;
      u32 a = pack2(sv[o + 0], sv[o + 1]);
      u32 bb = pack2(sv[o + 4], sv[o + 5]);
      u32 c = pack2(sv[o + 2], sv[o + 3]);
      u32 d = pack2(sv[o + 6], sv[o + 7]);
      plswap(a, bb);
      plswap(c, d);
      union { u32 u[4]; s16x8 v; } fr;
      fr.u[0] = a; fr.u[1] = c; fr.u[2] = bb; fr.u[3] = d;
      pa[g] = fr.v;
    }

    // ---- O += P V ----
    __builtin_amdgcn_s_setprio(1);
#pragma unroll
    for (int j = 0; j < 4; ++j) {
      s16x8 vf0 = *(const s16x8*)&vb[off[0][j]];
      acc0 = __builtin_amdgcn_mfma_f32_32x32x16_bf16(pa[j], vf0, acc0, 0, 0, 0);
      s16x8 vf1 = *(const s16x8*)&vb[off[1][j]];
      acc1 = __builtin_amdgcn_mfma_f32_32x32x16_bf16(pa[j], vf1, acc1, 0, 0, 0);
    }
    __builtin_amdgcn_s_setprio(0);
  }

  // ---- single deferred cross-half reduction of lsum ----
  lsum += __shfl_xor(lsum, 32);

  // ---- merge the two KV halves through LDS (plain add; no rescale) ----
  __syncthreads();
  float* mbuf = (float*)&k_t[0][0][0];
  float* ml   = (float*)&v_t[0][0][0];

  if (half == 1) {
    if (hi == 0) ml[wq * 32 + l31] = lsum;
#pragma unroll
    for (int r = 0; r < 16; ++r) {
      mbuf[((wq * 32 + r) * 64) + l] = acc0[r];
      mbuf[((wq * 32 + 16 + r) * 64) + l] = acc1[r];
    }
  }
  __syncthreads();

  if (half == 0) {
    float s_b = ml[wq * 32 + l31];
    float lstar = lsum + s_b;
    int lsi = __float_as_int(lstar);
#pragma unroll
    for (int r = 0; r < 16; ++r) {
      int ql = (r & 3) + 8 * (r >> 2) + 4 * hi;
      float ls = __int_as_float(__builtin_amdgcn_ds_bpermute(ql << 2, lsi));
      float o0 = acc0[r] + mbuf[((wq * 32 + r) * 64) + l];
      float o1 = acc1[r] + mbuf[((wq * 32 + 16 + r) * 64) + l];
      float inv = 1.f / ls;
      int q = qb * 128 + wq * 32 + ql;
      long ob = ((long)(b * N_ + q) * H_ + h) * 64 + l31;
      O[ob] = f2bf(o0 * inv);
      O[ob + 32] = f2bf(o1 * inv);
    }
  }
}

// ---------- launch ----------
extern "C" void kernel_launch(void* const* d_in, const int* in_sizes, int n_in,
                              void* d_out, int out_size, void* d_ws, size_t ws_size,
                              hipStream_t stream) {
  const float* x      = (const float*)d_in[0];
  const float* qkv_w  = (const float*)d_in[1];
  const float* q_g    = (const float*)d_in[2];
  const float* q_b    = (const float*)d_in[3];
  const float* k_g    = (const float*)d_in[4];
  const float* k_b    = (const float*)d_in[5];
  const float* proj_w = (const float*)d_in[6];
  const float* proj_b = (const float*)d_in[7];
  float* out = (float*)d_out;

  char* ws = (char*)d_ws;
  // byte offsets (all 256-aligned)
  u16* xb     = (u16*)(ws + 0);                       //  8 MB  [4096][1024]
  u16* wqkvT  = (u16*)(ws + 8388608);                 //  6 MB  [3072][1024]
  u16* wprojT = (u16*)(ws + 14680064);                //  2 MB  [1024][1024]
  u16* Qh     = (u16*)(ws + 16777216);                //  8 MB  [32][2048][64]
  u16* Kh     = (u16*)(ws + 25165824);                //  8 MB
  u16* Vt     = (u16*)(ws + 41943040);                //  8 MB  [32][64][2048]
  u16* attnO  = xb;                                   // reuse (xb dead after QKV GEMM)

  k_prep<<<8192, 256, 0, stream>>>(x, xb, qkv_w, wqkvT, proj_w, wprojT);
  k_gemm_qkv_ln<<<768, 256, 0, stream>>>(xb, wqkvT, q_g, q_b, k_g, k_b, Qh, Kh, Vt);
  k_attn<<<512, 512, 0, stream>>>(Qh, Kh, Vt, attnO);
  k_gemm_proj<<<512, 256, 0, stream>>>(attnO, wprojT, out, proj_b, BN_, C_, C_);
}

// Round 22
// 112.837 us; speedup vs baseline: 1.0312x; 1.0183x over previous
//
#include <hip/hip_runtime.h>

typedef unsigned short u16;
typedef unsigned int u32;
typedef float f32x4 __attribute__((ext_vector_type(4)));
typedef float f32x16 __attribute__((ext_vector_type(16)));
typedef short s16x8 __attribute__((ext_vector_type(8)));

#define B_ 2
#define N_ 2048
#define C_ 1024
#define H_ 16
#define BN_ (B_*N_)   // 4096 rows

#define EXP2F(x) __builtin_amdgcn_exp2f(x)   // v_exp_f32 (base-2 native)

// ---------- helpers ----------
__device__ __forceinline__ u16 f2bf(float f) {
  union { float f; unsigned u; } c; c.f = f;
  unsigned u = c.u;
  u = (u + 0x7fffu + ((u >> 16) & 1u)) >> 16;   // RNE
  return (u16)u;
}
__device__ __forceinline__ float bf2f(u16 h) {
  union { unsigned u; float f; } c; c.u = ((unsigned)h) << 16;
  return c.f;
}
// pack two f32 -> u32 of 2 bf16 via HW cvt (lo16 = src0, hi16 = src1; RNE)
__device__ __forceinline__ u32 pack2(float lo, float hi) {
  u32 r;
  asm("v_cvt_pk_bf16_f32 %0, %1, %2" : "=v"(r) : "v"(lo), "v"(hi));
  return r;
}
// swap: new_a[hi lanes] = old_b[partner], new_b[lo lanes] = old_a[partner].
// a and b MUST be distinct values (aliased self-swap was the R4 bug).
__device__ __forceinline__ void plswap(u32& a, u32& b) {
  asm volatile("v_permlane32_swap_b32 %0, %1" : "+v"(a), "+v"(b));
}
__device__ __forceinline__ void gload16(const u16* g, u16* l) {
  __builtin_amdgcn_global_load_lds(
      (const __attribute__((address_space(1))) unsigned*)g,
      (__attribute__((address_space(3))) unsigned*)l, 16, 0, 0);
}

// ---------- fused prep: x cast + qkv_w transpose + proj_w transpose ----------
__global__ __launch_bounds__(256) void k_prep(const float* __restrict__ x,
                                              u16* __restrict__ xb,
                                              const float* __restrict__ qkv_w,
                                              u16* __restrict__ wqkvT,
                                              const float* __restrict__ proj_w,
                                              u16* __restrict__ wprojT) {
  __shared__ float t[32][33];
  int bid = blockIdx.x;
  int tid = threadIdx.x;
  if (bid < 4096) {
    int i = bid * 256 + tid;
    float4 v = ((const float4*)x)[i];
    ushort4 r;
    r.x = f2bf(v.x); r.y = f2bf(v.y); r.z = f2bf(v.z); r.w = f2bf(v.w);
    ((ushort4*)xb)[i] = r;
    return;
  }
  const float* W; u16* Wt; int R, Cc, bx, by;
  if (bid < 7168) {
    int b = bid - 4096;
    bx = b % 96; by = b / 96;
    W = qkv_w; Wt = wqkvT; R = C_; Cc = 3 * C_;
  } else {
    int b = bid - 7168;
    bx = b & 31; by = b >> 5;
    W = proj_w; Wt = wprojT; R = C_; Cc = C_;
  }
  int tx = tid & 31, ty = tid >> 5;
  int c0 = bx * 32, r0 = by * 32;
#pragma unroll
  for (int i = 0; i < 4; ++i)
    t[ty + i * 8][tx] = W[(long)(r0 + ty + i * 8) * Cc + c0 + tx];
  __syncthreads();
#pragma unroll
  for (int i = 0; i < 4; ++i)
    Wt[(long)(c0 + ty + i * 8) * R + r0 + tx] = f2bf(t[tx][ty + i * 8]);
}

// ---------- QKV GEMM BK=64 (R17-verified 128x128) + fused LN + V-transpose ----------
// 2-buffer LDS (64KB), counted vmcnt(8); T2 XOR swizzle. Natural block order
// (XCD swizzle measured neutral-to-negative here — issue-bound, not HBM-bound).
__global__ __launch_bounds__(256) void k_gemm_qkv_ln(const u16* __restrict__ A,
                                                     const u16* __restrict__ Bt,
                                                     const float* __restrict__ qg,
                                                     const float* __restrict__ qbeta,
                                                     const float* __restrict__ kg,
                                                     const float* __restrict__ kbeta,
                                                     u16* __restrict__ Qh,
                                                     u16* __restrict__ Kh,
                                                     u16* __restrict__ Vt) {
  const int K = C_;
  __shared__ u16 smem[32768];            // 64KB: a_t[2] @0, b_t[2] @16384
  int tid = threadIdx.x;
  int w = tid >> 6, l = tid & 63;
  int l15 = l & 15, lhi = l >> 4;
  int wm = w >> 1, wn = w & 1;
  int rowA = l >> 3;
  int colA = ((l & 7) ^ (rowA & 7)) * 8;     // pre-swizzled source slot
  int x0 = (lhi ^ (l15 & 7)) * 8;            // phys frag offsets (loop-invariant)
  int x1 = ((4 + lhi) ^ (l15 & 7)) * 8;
  const u16* Ab = A + (long)blockIdx.y * 128 * K;
  const u16* Bb = Bt + (long)blockIdx.x * 128 * K;
  f32x4 acc[4][4];
#pragma unroll
  for (int m = 0; m < 4; ++m)
#pragma unroll
    for (int n = 0; n < 4; ++n)
      acc[m][n] = (f32x4){0.f, 0.f, 0.f, 0.f};

  auto STAGE = [&](int k0, int bi) {
    u16* at = smem + bi * 8192;
    u16* bt = smem + 16384 + bi * 8192;
#pragma unroll
    for (int i = 0; i < 4; ++i) {
      int ci = i * 4 + w;
      gload16(Ab + (long)(ci * 8 + rowA) * K + k0 + colA, &at[ci * 512]);
      gload16(Bb + (long)(ci * 8 + rowA) * K + k0 + colA, &bt[ci * 512]);
    }
  };

  const int NS = K / 64;  // 16
  STAGE(0, 0);
  for (int t = 0; t < NS; ++t) {
    __builtin_amdgcn_s_barrier();          // compute on buf (t-1)&1 done
    if (t + 1 < NS) {
      STAGE((t + 1) * 64, (t + 1) & 1);
      asm volatile("s_waitcnt vmcnt(8)" ::: "memory");
    } else {
      asm volatile("s_waitcnt vmcnt(0)" ::: "memory");
    }
    __builtin_amdgcn_s_barrier();          // tile t staged for all waves
    const u16* at = smem + (t & 1) * 8192;
    const u16* bt = smem + 16384 + (t & 1) * 8192;
#pragma unroll
    for (int kk = 0; kk < 2; ++kk) {
      int xo = kk ? x1 : x0;
      s16x8 af[4], bfr[4];
#pragma unroll
      for (int m = 0; m < 4; ++m)
        af[m] = *(const s16x8*)&at[(wm * 64 + m * 16 + l15) * 64 + xo];
#pragma unroll
      for (int n = 0; n < 4; ++n)
        bfr[n] = *(const s16x8*)&bt[(wn * 64 + n * 16 + l15) * 64 + xo];
#pragma unroll
      for (int m = 0; m < 4; ++m)
#pragma unroll
        for (int n = 0; n < 4; ++n)
          acc[m][n] = __builtin_amdgcn_mfma_f32_16x16x32_bf16(af[m], bfr[n], acc[m][n], 0, 0, 0);
    }
  }

  // ---- fused epilogue ----
  int cb = blockIdx.x * 128 + wn * 64;   // warp col base (64 cols = 1 head)
  int s = cb >> 10;                      // 0=q 1=k 2=v
  int h = (cb & 1023) >> 6;
  int rowbase = blockIdx.y * 128 + wm * 64;

  if (s == 2) {
    // ---- V: in-LDS warp-local 64x64 transpose, write Vt directly ----
    __syncthreads();                     // staging LDS now reusable
    u16* tbuf = smem + w * 4608;         // 64 rows(d) x pitch 72 (9216 B/warp)
    u32* tb32 = (u32*)tbuf;
#pragma unroll
    for (int m = 0; m < 4; ++m)
#pragma unroll
      for (int n = 0; n < 4; ++n) {
        int d = n * 16 + l15;
#pragma unroll
        for (int r = 0; r < 4; r += 2)
          tb32[d * 36 + m * 8 + lhi * 2 + (r >> 1)] =
              pack2(acc[m][n][r], acc[m][n][r + 1]);
      }
    int b = rowbase >> 11;
    int nnb = rowbase & (N_ - 1);
    int bhv = b * H_ + h;
    int ch = (l & 7) * 8;
#pragma unroll
    for (int i = 0; i < 8; ++i) {
      int dl = i * 8 + (l >> 3);
      s16x8 vv = *(const s16x8*)&tbuf[dl * 72 + ch];
      *(s16x8*)&Vt[(long)(bhv * 64 + dl) * N_ + nnb + ch] = vv;
    }
  } else {
    const float* g = (s == 0) ? qg : kg;
    const float* be = (s == 0) ? qbeta : kbeta;
    u16* Oh = (s == 0) ? Qh : Kh;
    float sc = (s == 0) ? 0.125f * 1.44269504089f : 1.f;   // fold log2(e)
    float gv[4], bv[4];
#pragma unroll
    for (int n = 0; n < 4; ++n) { gv[n] = g[n * 16 + l15]; bv[n] = be[n * 16 + l15]; }
#pragma unroll
    for (int m = 0; m < 4; ++m) {
#pragma unroll
      for (int r = 0; r < 4; ++r) {
        float t = (acc[m][0][r] + acc[m][1][r]) + (acc[m][2][r] + acc[m][3][r]);
        t += __shfl_xor(t, 1); t += __shfl_xor(t, 2);
        t += __shfl_xor(t, 4); t += __shfl_xor(t, 8);
        float mean = t * (1.f / 64.f);
        float v0 = acc[m][0][r] - mean, v1 = acc[m][1][r] - mean;
        float v2 = acc[m][2][r] - mean, v3 = acc[m][3][r] - mean;
        float q2 = (v0 * v0 + v1 * v1) + (v2 * v2 + v3 * v3);
        q2 += __shfl_xor(q2, 1); q2 += __shfl_xor(q2, 2);
        q2 += __shfl_xor(q2, 4); q2 += __shfl_xor(q2, 8);
        float rs = rsqrtf(q2 * (1.f / 64.f) + 1e-6f);
        int row = rowbase + m * 16 + lhi * 4 + r;
        int b = row >> 11, nn = row & (N_ - 1);
        long ob = ((long)(b * H_ + h) * N_ + nn) * 64;
        float vv[4] = {v0, v1, v2, v3};
#pragma unroll
        for (int n = 0; n < 4; ++n)
          Oh[ob + n * 16 + l15] = f2bf(sc * (gv[n] * vv[n] * rs + bv[n]));
      }
    }
  }
}

// ---------- proj GEMM: 128x64 tiles (R17-verified; 512 blocks, 2/CU) ----------
__global__ __launch_bounds__(256) void k_gemm_proj(const u16* __restrict__ A,
                                                   const u16* __restrict__ Bt,
                                                   float* __restrict__ Cout,
                                                   const float* __restrict__ bias,
                                                   int M, int N, int K) {
  __shared__ u16 a_t[2][128 * 64];   // 32KB
  __shared__ u16 b_t[2][64 * 64];    // 16KB
  int tid = threadIdx.x;
  int w = tid >> 6, l = tid & 63;
  int l15 = l & 15, lhi = l >> 4;
  int rowA = l >> 3;
  int colA = ((l & 7) ^ (rowA & 7)) * 8;
  int x0 = (lhi ^ (l15 & 7)) * 8;
  int x1 = ((4 + lhi) ^ (l15 & 7)) * 8;
  const u16* Ab = A + (long)blockIdx.y * 128 * K;
  const u16* Bb = Bt + (long)blockIdx.x * 64 * K;
  f32x4 acc[2][4];
#pragma unroll
  for (int m = 0; m < 2; ++m)
#pragma unroll
    for (int n = 0; n < 4; ++n)
      acc[m][n] = (f32x4){0.f, 0.f, 0.f, 0.f};

  auto STAGE = [&](int k0, int bi) {
#pragma unroll
    for (int i = 0; i < 4; ++i) {
      int ci = i * 4 + w;
      gload16(Ab + (long)(ci * 8 + rowA) * K + k0 + colA, &a_t[bi][ci * 512]);
    }
#pragma unroll
    for (int i = 0; i < 2; ++i) {
      int ci = i * 4 + w;
      gload16(Bb + (long)(ci * 8 + rowA) * K + k0 + colA, &b_t[bi][ci * 512]);
    }
  };

  const int NS = 1024 / 64;  // 16
  STAGE(0, 0);
  for (int t = 0; t < NS; ++t) {
    __builtin_amdgcn_s_barrier();
    if (t + 1 < NS) {
      STAGE((t + 1) * 64, (t + 1) & 1);
      asm volatile("s_waitcnt vmcnt(6)" ::: "memory");
    } else {
      asm volatile("s_waitcnt vmcnt(0)" ::: "memory");
    }
    __builtin_amdgcn_s_barrier();
    const u16* at = a_t[t & 1];
    const u16* bt = b_t[t & 1];
#pragma unroll
    for (int kk = 0; kk < 2; ++kk) {
      int xo = kk ? x1 : x0;
      s16x8 af[2], bfr[4];
#pragma unroll
      for (int m = 0; m < 2; ++m)
        af[m] = *(const s16x8*)&at[(w * 32 + m * 16 + l15) * 64 + xo];
#pragma unroll
      for (int n = 0; n < 4; ++n)
        bfr[n] = *(const s16x8*)&bt[(n * 16 + l15) * 64 + xo];
#pragma unroll
      for (int m = 0; m < 2; ++m)
#pragma unroll
        for (int n = 0; n < 4; ++n)
          acc[m][n] = __builtin_amdgcn_mfma_f32_16x16x32_bf16(af[m], bfr[n], acc[m][n], 0, 0, 0);
    }
  }
#pragma unroll
  for (int m = 0; m < 2; ++m) {
#pragma unroll
    for (int n = 0; n < 4; ++n) {
      int col = blockIdx.x * 64 + n * 16 + l15;
#pragma unroll
      for (int r = 0; r < 4; ++r) {
        int row = blockIdx.y * 128 + w * 32 + m * 16 + lhi * 4 + r;
        Cout[(long)row * N + col] = acc[m][n][r] + bias[col];
      }
    }
  }
}

// ---------- flash attention (R17-verified): 8-wave, in-block KV split ----------
// Qh pre-scaled by (1/8)*log2(e); exp2-domain NO-MAX softmax. Waves 0-3:
// keys 0..1023; waves 4-7: keys 1024..2047. permlane32_swap P-pack; deferred
// lsum cross-half. Grid 1D 512, XCD swizzle.
__global__ __launch_bounds__(512, 4) void k_attn(const u16* __restrict__ Qh,
                                                 const u16* __restrict__ Kh,
                                                 const u16* __restrict__ Vt,
                                                 u16* __restrict__ O) {
  __shared__ u16 k_t[2][2][64 * 64];   // [half][buf][.]  32KB
  __shared__ u16 v_t[2][2][64 * 64];   //                 32KB
  int tid = threadIdx.x;
  int w = tid >> 6, l = tid & 63;
  int half = w >> 2, wq = w & 3;
  int l31 = l & 31, hi = l >> 5;
  int id = blockIdx.x;
  int swz = (id & 7) * 64 + (id >> 3);
  int bh = swz >> 4, qb = swz & 15;
  int b = bh >> 4, h = bh & 15;
  const u16* Qb = Qh + ((long)bh * N_ + qb * 128 + wq * 32) * 64;
  const u16* Kb = Kh + ((long)bh * N_ + half * 1024) * 64;
  const u16* Vb = Vt + (long)bh * 64 * N_ + half * 1024;

  s16x8 qf[4];
#pragma unroll
  for (int j = 0; j < 4; ++j)
    qf[j] = *(const s16x8*)&Qb[l31 * 64 + j * 16 + hi * 8];

  f32x16 acc0, acc1;
#pragma unroll
  for (int i = 0; i < 16; ++i) { acc0[i] = 0.f; acc1[i] = 0.f; }
  float lsum = 0.f;   // lane-local partial; cross-half once at end

  int off[2][4];
#pragma unroll
  for (int t = 0; t < 2; ++t)
#pragma unroll
    for (int j = 0; j < 4; ++j)
      off[t][j] = (t * 32 + l31) * 64 + (((j * 2 + hi) ^ (l & 7)) * 8);

  int srow = l >> 3;
  int scol = ((l & 7) ^ srow) * 8;

  auto STAGE = [&](int kt, int bi) {
#pragma unroll
    for (int i = 0; i < 2; ++i) {
      int ci = i * 4 + wq;
      gload16(Kb + (long)(kt + ci * 8 + srow) * 64 + scol, &k_t[half][bi][ci * 512]);
      gload16(Vb + (long)(ci * 8 + srow) * N_ + kt + scol, &v_t[half][bi][ci * 512]);
    }
  };

  const int NT = 16;   // 1024 keys per half / 64
  STAGE(0, 0);

  for (int t = 0; t < NT; ++t) {
    __builtin_amdgcn_s_barrier();
    if (t + 1 < NT) {
      STAGE((t + 1) * 64, (t + 1) & 1);
      asm volatile("s_waitcnt vmcnt(4)" ::: "memory");
    } else {
      asm volatile("s_waitcnt vmcnt(0)" ::: "memory");
    }
    __builtin_amdgcn_s_barrier();
    const u16* kb = k_t[half][t & 1];
    const u16* vb = v_t[half][t & 1];

    // ---- S^T = mfma(K, Q) ----
    f32x16 s0, s1;
#pragma unroll
    for (int i = 0; i < 16; ++i) { s0[i] = 0.f; s1[i] = 0.f; }
    __builtin_amdgcn_s_setprio(1);
#pragma unroll
    for (int j = 0; j < 4; ++j) {
      s16x8 kf0 = *(const s16x8*)&kb[off[0][j]];
      s0 = __builtin_amdgcn_mfma_f32_32x32x16_bf16(kf0, qf[j], s0, 0, 0, 0);
      s16x8 kf1 = *(const s16x8*)&kb[off[1][j]];
      s1 = __builtin_amdgcn_mfma_f32_32x32x16_bf16(kf1, qf[j], s1, 0, 0, 0);
    }
    __builtin_amdgcn_s_setprio(0);

    // ---- P = exp2(S), lane-local row-sum ----
#pragma unroll
    for (int i = 0; i < 16; ++i) {
      s0[i] = EXP2F(s0[i]);
      s1[i] = EXP2F(s1[i]);
    }
    f32x16 sm;
#pragma unroll
    for (int i = 0; i < 16; ++i) sm[i] = s0[i] + s1[i];
#pragma unroll
    for (int i = 0; i < 8; ++i) sm[i] += sm[i + 8];
#pragma unroll
    for (int i = 0; i < 4; ++i) sm[i] += sm[i + 4];
    lsum += (sm[0] + sm[1]) + (sm[2] + sm[3]);

    // ---- pack P into PV A-fragments (permlane32_swap) ----
    s16x8 pa[4];
#pragma unroll
    for (int g = 0; g < 4; ++g) {
      const f32x16& sv = (g < 2) ? s0 : s1;
      int o = (g & 1) * 8;
      u32 a = pack2(sv[o + 0], sv[o + 1]);
      u32 bb = pack2(sv[o + 4], sv[o + 5]);
      u32 c = pack2(sv[o + 2], sv[o + 3]);
      u32 d = pack2(sv[o + 6], sv[o + 7]);
      plswap(a, bb);
      plswap(c, d);
      union { u32 u[4]; s16x8 v; } fr;
      fr.u[0] = a; fr.u[1] = c; fr.u[2] = bb; fr.u[3] = d;
      pa[g] = fr.v;
    }

    // ---- O += P V ----
    __builtin_amdgcn_s_setprio(1);
#pragma unroll
    for (int j = 0; j < 4; ++j) {
      s16x8 vf0 = *(const s16x8*)&vb[off[0][j]];
      acc0 = __builtin_amdgcn_mfma_f32_32x32x16_bf16(pa[j], vf0, acc0, 0, 0, 0);
      s16x8 vf1 = *(const s16x8*)&vb[off[1][j]];
      acc1 = __builtin_amdgcn_mfma_f32_32x32x16_bf16(pa[j], vf1, acc1, 0, 0, 0);
    }
    __builtin_amdgcn_s_setprio(0);
  }

  // ---- single deferred cross-half reduction of lsum ----
  lsum += __shfl_xor(lsum, 32);

  // ---- merge the two KV halves through LDS (plain add; no rescale) ----
  __syncthreads();
  float* mbuf = (float*)&k_t[0][0][0];
  float* ml   = (float*)&v_t[0][0][0];

  if (half == 1) {
    if (hi == 0) ml[wq * 32 + l31] = lsum;
#pragma unroll
    for (int r = 0; r < 16; ++r) {
      mbuf[((wq * 32 + r) * 64) + l] = acc0[r];
      mbuf[((wq * 32 + 16 + r) * 64) + l] = acc1[r];
    }
  }
  __syncthreads();

  if (half == 0) {
    float s_b = ml[wq * 32 + l31];
    float lstar = lsum + s_b;
    int lsi = __float_as_int(lstar);
#pragma unroll
    for (int r = 0; r < 16; ++r) {
      int ql = (r & 3) + 8 * (r >> 2) + 4 * hi;
      float ls = __int_as_float(__builtin_amdgcn_ds_bpermute(ql << 2, lsi));
      float o0 = acc0[r] + mbuf[((wq * 32 + r) * 64) + l];
      float o1 = acc1[r] + mbuf[((wq * 32 + 16 + r) * 64) + l];
      float inv = 1.f / ls;
      int q = qb * 128 + wq * 32 + ql;
      long ob = ((long)(b * N_ + q) * H_ + h) * 64 + l31;
      O[ob] = f2bf(o0 * inv);
      O[ob + 32] = f2bf(o1 * inv);
    }
  }
}

// ---------- launch ----------
extern "C" void kernel_launch(void* const* d_in, const int* in_sizes, int n_in,
                              void* d_out, int out_size, void* d_ws, size_t ws_size,
                              hipStream_t stream) {
  const float* x      = (const float*)d_in[0];
  const float* qkv_w  = (const float*)d_in[1];
  const float* q_g    = (const float*)d_in[2];
  const float* q_b    = (const float*)d_in[3];
  const float* k_g    = (const float*)d_in[4];
  const float* k_b    = (const float*)d_in[5];
  const float* proj_w = (const float*)d_in[6];
  const float* proj_b = (const float*)d_in[7];
  float* out = (float*)d_out;

  char* ws = (char*)d_ws;
  // byte offsets (all 256-aligned)
  u16* xb     = (u16*)(ws + 0);                       //  8 MB  [4096][1024]
  u16* wqkvT  = (u16*)(ws + 8388608);                 //  6 MB  [3072][1024]
  u16* wprojT = (u16*)(ws + 14680064);                //  2 MB  [1024][1024]
  u16* Qh     = (u16*)(ws + 16777216);                //  8 MB  [32][2048][64]
  u16* Kh     = (u16*)(ws + 25165824);                //  8 MB
  u16* Vt     = (u16*)(ws + 41943040);                //  8 MB  [32][64][2048]
  u16* attnO  = xb;                                   // reuse (xb dead after QKV GEMM)

  k_prep<<<8192, 256, 0, stream>>>(x, xb, qkv_w, wqkvT, proj_w, wprojT);
  k_gemm_qkv_ln<<<dim3(24, 32), 256, 0, stream>>>(xb, wqkvT, q_g, q_b, k_g, k_b, Qh, Kh, Vt);
  k_attn<<<512, 512, 0, stream>>>(Qh, Kh, Vt, attnO);
  k_gemm_proj<<<dim3(16, 32), 256, 0, stream>>>(attnO, wprojT, out, proj_b, BN_, C_, C_);
}